// Round 7
// baseline (858.947 us; speedup 1.0000x reference)
//
#include <hip/hip_runtime.h>
#include <math.h>

// ============ DIAGNOSIS BUILD ============
// Each kernel repeats its (idempotent) body REP_* times so single dispatches
// exceed the ~39us harness fills and surface in rocprof top-5 with counters.
// Revert REP_* to 1 after reading the profile.
#define REP_PACK 32
#define REP_P1   16
#define REP_P2   16

// Problem constants (fixed by the reference)
constexpr int B_    = 8;
constexpr int CIN_  = 128;
constexpr int H_    = 28;
constexpr int W_    = 28;
constexpr int COUT_ = 256;
constexpr int OH_   = 28;
constexpr int OW_   = 28;
constexpr int L_    = OH_ * OW_;     // 784
constexpr int N_    = B_ * L_;       // 6272
constexpr int NCB_  = 64;
constexpr int K_    = 16;
constexpr int SUB_  = 18;            // 2 channels x 9 taps

// ws layout (byte offsets)
constexpr size_t WS_IDXT = 0;                  // N_*64 uchar = 401408 B
constexpr size_t WS_LUT8 = 0x100000;           // 262144 uchar = 256 KB
constexpr size_t WS_CFT  = 0x180000;           // 64*18*16 f32 = 73728 B
constexpr size_t WS_Y2   = 0x1A0000;           // 1024 f32
constexpr size_t WS_BF2  = 0x1A8000;           // 256 f32 (bias + folded consts)

// ---------------------------------------------------------------------------
// Pre-pass: LUT int32 -> biased uint8 (v+128); centroids -> k-major
// float(c_q - c_z); y2 (double) -> f32; bias -> dequant f32 with the
// (8192 + 64*lut_z)*lut_s constant folded in.
// ---------------------------------------------------------------------------
__global__ __launch_bounds__(256) void amm_pack(
    const int* __restrict__ lut_q, const float* __restrict__ lut_s,
    const int* __restrict__ lut_z,
    const int* __restrict__ c_q, const float* __restrict__ c_s,
    const int* __restrict__ c_z, const float* __restrict__ x_s,
    const int* __restrict__ bias_q, const float* __restrict__ bias_s,
    const int* __restrict__ bias_z,
    unsigned char* __restrict__ lut8, float* __restrict__ cft,
    float* __restrict__ y2f, float* __restrict__ biasf2)
{
    const int bid = blockIdx.x, tid = threadIdx.x;
    for (int rep = 0; rep < REP_PACK; ++rep) {
    if (bid < 256) {
        const int i = bid * 1024 + tid * 4;      // covers 262144 exactly
        const int4 v = *(const int4*)(lut_q + i);
        uchar4 o;
        o.x = (unsigned char)(v.x + 128);
        o.y = (unsigned char)(v.y + 128);
        o.z = (unsigned char)(v.z + 128);
        o.w = (unsigned char)(v.w + 128);
        *(uchar4*)(lut8 + i) = o;
    } else if (bid < 260) {
        const int t = (bid - 256) * 256 + tid;   // (cb,k) pair, 1024 total
        if (t < NCB_ * K_) {
            const int cb = t >> 4, k = t & 15;
            const int zc = c_z[cb];
            const double csf = (double)c_s[cb];
            const double den = (double)x_s[0] * csf;
            double s2 = 0.0;
            for (int s = 0; s < SUB_; ++s) {
                const int ci = c_q[t * SUB_ + s] - zc;
                cft[(cb * SUB_ + s) * 16 + k] = (float)ci;   // exact small int
                const double d = (double)ci * csf;
                s2 += d * d;
            }
            y2f[t] = (float)(int)rint(s2 / den);     // < 2^24 -> exact in f32
        }
    } else {
        // biasf2[co] = dequant bias - (8192 + 64*lz)*ls   (folded constant)
        const double ls = (double)lut_s[0];
        const double c0 = (8192.0 + 64.0 * (double)lut_z[0]) * ls;
        biasf2[tid] = (float)((double)(bias_q[tid] - bias_z[0]) *
                              (double)bias_s[0] - c0);
    }
    asm volatile("" ::: "memory");
    }
}

// ---------------------------------------------------------------------------
// Phase 1: per (codebook, position) argmin over 16 centroids.
// dist = y2[k] - 2*dot; dot exact integer in f32. Centroids k-major, block-
// uniform -> scalar loads. Output: bytes idx_t[n*64+cb].
// ---------------------------------------------------------------------------
__global__ __launch_bounds__(256) void amm_phase1(
    const int* __restrict__ x_q, const int* __restrict__ x_z,
    const float* __restrict__ cft, const float* __restrict__ y2f,
    unsigned char* __restrict__ idx_t)
{
    const int cb  = blockIdx.x;
    const int tid = threadIdx.x;
    const int n   = blockIdx.y * 256 + tid;
    if (n >= N_) return;

    const float* __restrict__ crow = cft + cb * (SUB_ * 16);  // [s][k]
    const float* __restrict__ yrow = y2f + cb * K_;

    for (int rep = 0; rep < REP_P1; ++rep) {
    const int xz = x_z[0];
    const int b  = n / L_;
    const int r  = n - b * L_;
    const int oh = r / OW_;
    const int ow = r - oh * OW_;

    float xi[SUB_];
    #pragma unroll
    for (int c2 = 0; c2 < 2; ++c2) {
        const int* base = x_q + (size_t)(b * CIN_ + 2 * cb + c2) * (H_ * W_);
        #pragma unroll
        for (int kh = 0; kh < 3; ++kh) {
            const int h = oh + kh - 1;
            #pragma unroll
            for (int kw = 0; kw < 3; ++kw) {
                const int w = ow + kw - 1;
                int v = 0;
                if ((unsigned)h < (unsigned)H_ && (unsigned)w < (unsigned)W_)
                    v = base[h * W_ + w] - xz;
                xi[c2 * 9 + kh * 3 + kw] = (float)v;
            }
        }
    }

    float dot[K_];
    #pragma unroll
    for (int k = 0; k < K_; ++k) dot[k] = 0.0f;
    #pragma unroll
    for (int s = 0; s < SUB_; ++s) {
        const float xs = xi[s];
        #pragma unroll
        for (int k = 0; k < K_; ++k)
            dot[k] = fmaf(xs, crow[s * 16 + k], dot[k]);
    }

    float bestd = 3.0e38f;
    int   bestk = 0;
    #pragma unroll
    for (int k = 0; k < K_; ++k) {
        const float d = fmaf(-2.0f, dot[k], yrow[k]);  // exact integer-valued
        if (d < bestd) { bestd = d; bestk = k; }       // strict < => first min
    }
    idx_t[(size_t)n * 64 + cb] = (unsigned char)bestk;
    asm volatile("" ::: "memory");
    }
}

// ---------------------------------------------------------------------------
// Phase 2: grid 1568 x 256; each WAVE owns one position. Biased-uint8 LUT:
// per row one dword (4 couts) per lane; unpack via masks into two u32 accs
// of packed u16 sums (max 64*255 = 16320, carry-free with plain adds).
// 16-deep load batches for ILP. Epilogue: LDS transpose; thread co writes
// int4 (4 consecutive r).
// ---------------------------------------------------------------------------
__global__ __launch_bounds__(256, 6) void amm_phase2(
    const unsigned char* __restrict__ idx_t, const unsigned char* __restrict__ lut8,
    const float* __restrict__ lut_s, const float* __restrict__ biasf2,
    const float* __restrict__ out_s, const int* __restrict__ out_z,
    int* __restrict__ out)
{
    const int tid  = threadIdx.x;
    const int lane = tid & 63;
    const int w    = __builtin_amdgcn_readfirstlane(tid >> 6);
    const int nb   = blockIdx.x * 4;
    const int b    = nb / L_;          // uniform; 784%4==0 so no b crossing
    const int r0   = nb - b * L_;
    const int pos  = w;                // wave id = position within block

    __shared__ unsigned int res[4][130];   // [pos][128 words = 256 couts] +pad

    for (int rep = 0; rep < REP_P2; ++rep) {
    // prefetch full 64-B idx row (uniform address -> scalar loads)
    const uint4* rp = (const uint4*)(idx_t + (size_t)(nb + pos) * 64);
    uint4 q[4];
    q[0] = rp[0]; q[1] = rp[1]; q[2] = rp[2]; q[3] = rp[3];

    unsigned int accLo = 0, accHi = 0;   // packed u16 pairs
    #pragma unroll
    for (int bt = 0; bt < 4; ++bt) {
        const unsigned int wrd[4] = {q[bt].x, q[bt].y, q[bt].z, q[bt].w};
        unsigned int t[16];
        #pragma unroll
        for (int i = 0; i < 16; ++i) {
            const unsigned int k = (wrd[i >> 2] >> (8 * (i & 3))) & 0xffu;
            const int cb = bt * 16 + i;
            t[i] = *(const unsigned int*)(lut8 +
                    ((size_t)((cb << 4) + k) << 8) + (lane << 2));
        }
        #pragma unroll
        for (int i = 0; i < 16; ++i) {
            accLo += t[i] & 0x00FF00FFu;          // couts 4L, 4L+2
            accHi += (t[i] >> 8) & 0x00FF00FFu;   // couts 4L+1, 4L+3
        }
    }

    res[pos][lane * 2]     = accLo;
    res[pos][lane * 2 + 1] = accHi;
    __syncthreads();

    // ---- epilogue: thread t owns cout = t; int4 store of 4 consecutive r ----
    const float lsf = lut_s[0];
    const float osf = out_s[0];
    const float ozf = (float)out_z[0];

    const int co   = tid;
    const int c    = co & 3;
    const int u    = (co >> 2) * 2 + (c & 1);  // word index within row
    const int half = c >> 1;                   // u16 half within word
    const float bf = biasf2[co];

    int4 ov;
    int* ovp = (int*)&ov;
    #pragma unroll
    for (int p = 0; p < 4; ++p) {
        const unsigned int vv = res[p][u];
        const int sv = (int)((vv >> (16 * half)) & 0xffffu);
        float f = (float)sv * lsf + bf;        // = dequant sum + bias
        f = fmaxf(f, 0.0f) / osf + ozf;
        f = fminf(fmaxf(f, -128.0f), 127.0f);
        ovp[p] = (int)rintf(f);
    }
    *(int4*)(out + (size_t)(b * COUT_ + co) * L_ + r0) = ov;
    __syncthreads();                 // protect res[] before next rep rewrites
    asm volatile("" ::: "memory");
    }
}

extern "C" void kernel_launch(void* const* d_in, const int* in_sizes, int n_in,
                              void* d_out, int out_size, void* d_ws, size_t ws_size,
                              hipStream_t stream)
{
    const int*   x_q    = (const int*)  d_in[0];
    const float* x_s    = (const float*)d_in[1];
    const int*   x_z    = (const int*)  d_in[2];
    const int*   c_q    = (const int*)  d_in[3];
    const float* c_s    = (const float*)d_in[4];
    const int*   c_z    = (const int*)  d_in[5];
    const int*   lut_q  = (const int*)  d_in[6];
    const float* lut_s  = (const float*)d_in[7];
    const int*   lut_z  = (const int*)  d_in[8];
    const int*   bias_q = (const int*)  d_in[9];
    const float* bias_s = (const float*)d_in[10];
    const int*   bias_z = (const int*)  d_in[11];
    const float* out_s  = (const float*)d_in[12];
    const int*   out_z  = (const int*)  d_in[13];

    char* ws = (char*)d_ws;
    unsigned char* idx_t = (unsigned char*)(ws + WS_IDXT);
    unsigned char* lut8  = (unsigned char*)(ws + WS_LUT8);
    float* cft    = (float*)(ws + WS_CFT);
    float* y2fp   = (float*)(ws + WS_Y2);
    float* biasf2 = (float*)(ws + WS_BF2);

    amm_pack<<<dim3(261), 256, 0, stream>>>(lut_q, lut_s, lut_z,
                                            c_q, c_s, c_z, x_s,
                                            bias_q, bias_s, bias_z,
                                            lut8, cft, y2fp, biasf2);

    dim3 g1(NCB_, (N_ + 255) / 256);
    amm_phase1<<<g1, 256, 0, stream>>>(x_q, x_z, cft, y2fp, idx_t);

    amm_phase2<<<dim3(N_ / 4), 256, 0, stream>>>(
        idx_t, lut8, lut_s, biasf2, out_s, out_z, (int*)d_out);
}

// Round 8
// 31.210 us; speedup vs baseline: 27.5219x; 27.5219x over previous
//
#include <hip/hip_runtime.h>
#include <math.h>

// Problem constants (fixed by the reference)
constexpr int B_    = 8;
constexpr int CIN_  = 128;
constexpr int H_    = 28;
constexpr int W_    = 28;
constexpr int COUT_ = 256;
constexpr int OH_   = 28;
constexpr int OW_   = 28;
constexpr int L_    = OH_ * OW_;     // 784
constexpr int N_    = B_ * L_;       // 6272
constexpr int NCB_  = 64;
constexpr int K_    = 16;
constexpr int SUB_  = 18;            // 2 channels x 9 taps

// ws layout (byte offsets). idx layout is now [cb][n] (cb-major).
constexpr size_t WS_IDX  = 0;                  // 64*6272 uchar = 401408 B
constexpr size_t WS_LUT8 = 0x100000;           // 262144 uchar = 256 KB
constexpr size_t WS_CFT  = 0x180000;           // 64*18*16 f32 = 73728 B
constexpr size_t WS_Y2   = 0x1A0000;           // 1024 f32
constexpr size_t WS_BF2  = 0x1A8000;           // 256 f32 (bias + folded consts)

// ---------------------------------------------------------------------------
// Pre-pass (unchanged from R6): LUT int32 -> biased uint8 (v+128); centroids
// -> k-major float(c_q - c_z); y2 (double) -> f32; bias -> dequant f32 with
// the (8192 + 64*lut_z)*lut_s constant folded in.
// ---------------------------------------------------------------------------
__global__ __launch_bounds__(256) void amm_pack(
    const int* __restrict__ lut_q, const float* __restrict__ lut_s,
    const int* __restrict__ lut_z,
    const int* __restrict__ c_q, const float* __restrict__ c_s,
    const int* __restrict__ c_z, const float* __restrict__ x_s,
    const int* __restrict__ bias_q, const float* __restrict__ bias_s,
    const int* __restrict__ bias_z,
    unsigned char* __restrict__ lut8, float* __restrict__ cft,
    float* __restrict__ y2f, float* __restrict__ biasf2)
{
    const int bid = blockIdx.x, tid = threadIdx.x;
    if (bid < 256) {
        const int i = bid * 1024 + tid * 4;      // covers 262144 exactly
        const int4 v = *(const int4*)(lut_q + i);
        uchar4 o;
        o.x = (unsigned char)(v.x + 128);
        o.y = (unsigned char)(v.y + 128);
        o.z = (unsigned char)(v.z + 128);
        o.w = (unsigned char)(v.w + 128);
        *(uchar4*)(lut8 + i) = o;
    } else if (bid < 260) {
        const int t = (bid - 256) * 256 + tid;   // (cb,k) pair, 1024 total
        if (t < NCB_ * K_) {
            const int cb = t >> 4, k = t & 15;
            const int zc = c_z[cb];
            const double csf = (double)c_s[cb];
            const double den = (double)x_s[0] * csf;
            double s2 = 0.0;
            for (int s = 0; s < SUB_; ++s) {
                const int ci = c_q[t * SUB_ + s] - zc;
                cft[(cb * SUB_ + s) * 16 + k] = (float)ci;   // exact small int
                const double d = (double)ci * csf;
                s2 += d * d;
            }
            y2f[t] = (float)(int)rint(s2 / den);     // < 2^24 -> exact in f32
        }
    } else {
        // biasf2[co] = dequant bias - (8192 + 64*lz)*ls   (folded constant)
        const double ls = (double)lut_s[0];
        const double c0 = (8192.0 + 64.0 * (double)lut_z[0]) * ls;
        biasf2[tid] = (float)((double)(bias_q[tid] - bias_z[0]) *
                              (double)bias_s[0] - c0);
    }
}

// ---------------------------------------------------------------------------
// Phase 1 v2: block = (cb, b). Stage the block's 2 input channels zero-padded
// 30x30 in LDS (no bounds checks; each x element loaded once globally).
// Centroids (k-major) + y2 staged in LDS. Thread t < 196 handles 4 positions
// {t, t+196, t+392, t+588}: taps in 72 VGPRs, k processed in 4 chunks of 4
// via broadcast float4 reads, fmaf accumulation (order identical to before ->
// bit-identical results). Coalesced byte stores to idx[cb][n].
// ---------------------------------------------------------------------------
__global__ __launch_bounds__(256, 2) void amm_phase1(
    const int* __restrict__ x_q, const int* __restrict__ x_z,
    const float* __restrict__ cft, const float* __restrict__ y2f,
    unsigned char* __restrict__ idx8)
{
    const int cb  = blockIdx.x;
    const int b   = blockIdx.y;
    const int tid = threadIdx.x;

    __shared__ float sx[2][900];     // 30x30 zero-padded, 7.2 KB
    __shared__ float c_lds[288];     // [s][k] k-major
    __shared__ float y2_lds[16];

    // zero the padded tiles
    for (int i = tid; i < 1800; i += 256) ((float*)sx)[i] = 0.0f;
    __syncthreads();

    const int xz = x_z[0];
    // fill interior: i = c2*784 + r
    for (int i = tid; i < 2 * 784; i += 256) {
        const int c2 = i >= 784;
        const int r  = i - c2 * 784;
        const int h  = r / 28;
        const int w  = r - h * 28;
        sx[c2][(h + 1) * 30 + (w + 1)] =
            (float)(x_q[(size_t)(b * CIN_ + 2 * cb + c2) * L_ + r] - xz);
    }
    for (int i = tid; i < 288; i += 256) c_lds[i] = cft[cb * 288 + i];
    if (tid < 16) y2_lds[tid] = y2f[cb * 16 + tid];
    __syncthreads();

    if (tid < 196) {
        // load taps for 4 interleaved positions
        float tap[4][SUB_];
        int   posr[4];
        #pragma unroll
        for (int ps = 0; ps < 4; ++ps) {
            const int p  = tid + 196 * ps;
            posr[ps] = p;
            const int oh = p / 28;
            const int ow = p - oh * 28;
            const int base = oh * 30 + ow;   // padded origin handles the -1
            #pragma unroll
            for (int c2 = 0; c2 < 2; ++c2)
                #pragma unroll
                for (int kh = 0; kh < 3; ++kh)
                    #pragma unroll
                    for (int kw = 0; kw < 3; ++kw)
                        tap[ps][c2 * 9 + kh * 3 + kw] =
                            sx[c2][base + kh * 30 + kw];
        }

        float bestd[4] = {3.0e38f, 3.0e38f, 3.0e38f, 3.0e38f};
        int   bestk[4] = {0, 0, 0, 0};

        #pragma unroll
        for (int kc = 0; kc < 4; ++kc) {
            float acc[4][4];
            #pragma unroll
            for (int ps = 0; ps < 4; ++ps)
                #pragma unroll
                for (int kk = 0; kk < 4; ++kk) acc[ps][kk] = 0.0f;

            #pragma unroll
            for (int s = 0; s < SUB_; ++s) {
                const float4 c4 = *(const float4*)&c_lds[s * 16 + kc * 4];
                #pragma unroll
                for (int ps = 0; ps < 4; ++ps) {
                    const float xs = tap[ps][s];
                    acc[ps][0] = fmaf(xs, c4.x, acc[ps][0]);
                    acc[ps][1] = fmaf(xs, c4.y, acc[ps][1]);
                    acc[ps][2] = fmaf(xs, c4.z, acc[ps][2]);
                    acc[ps][3] = fmaf(xs, c4.w, acc[ps][3]);
                }
            }
            // argmin update, k ascending (strict < => first-occurrence min)
            #pragma unroll
            for (int kk = 0; kk < 4; ++kk) {
                const float yk = y2_lds[kc * 4 + kk];
                #pragma unroll
                for (int ps = 0; ps < 4; ++ps) {
                    const float d = fmaf(-2.0f, acc[ps][kk], yk);
                    if (d < bestd[ps]) { bestd[ps] = d; bestk[ps] = kc * 4 + kk; }
                }
            }
        }

        unsigned char* op = idx8 + (size_t)cb * N_ + b * L_;
        #pragma unroll
        for (int ps = 0; ps < 4; ++ps)
            op[posr[ps]] = (unsigned char)bestk[ps];   // coalesced across lanes
    }
}

// ---------------------------------------------------------------------------
// Phase 2: grid 1568 x 256; each WAVE owns one position. Biased-uint8 LUT:
// per row one dword (4 couts) per lane; unpack via masks into two u32 accs
// of packed u16 sums (max 64*255 = 16320, carry-free with plain adds).
// idx now [cb][n]: per bt-chunk, 16 uniform dword loads (nb dword-aligned,
// stride 6272) give the 4 positions' bytes per cb. 16-deep load batches for
// ILP. Epilogue: LDS transpose; thread co writes int4 (4 consecutive r).
// ---------------------------------------------------------------------------
__global__ __launch_bounds__(256, 6) void amm_phase2(
    const unsigned char* __restrict__ idx8, const unsigned char* __restrict__ lut8,
    const float* __restrict__ lut_s, const float* __restrict__ biasf2,
    const float* __restrict__ out_s, const int* __restrict__ out_z,
    int* __restrict__ out)
{
    const int tid  = threadIdx.x;
    const int lane = tid & 63;
    const int w    = __builtin_amdgcn_readfirstlane(tid >> 6);
    const int nb   = blockIdx.x * 4;
    const int b    = nb / L_;          // uniform; 784%4==0 so no b crossing
    const int r0   = nb - b * L_;
    const int pos  = w;                // wave id = position within block
    const int sh   = 8 * pos;

    __shared__ unsigned int res[4][130];   // [pos][128 words = 256 couts] +pad

    unsigned int accLo = 0, accHi = 0;   // packed u16 pairs
    #pragma unroll
    for (int bt = 0; bt < 4; ++bt) {
        unsigned int kw[16];
        #pragma unroll
        for (int i = 0; i < 16; ++i) {
            const int cbi = bt * 16 + i;
            kw[i] = *(const unsigned int*)(idx8 + (size_t)cbi * N_ + nb);
        }
        unsigned int t[16];
        #pragma unroll
        for (int i = 0; i < 16; ++i) {
            const unsigned int k = (kw[i] >> sh) & 0xffu;
            const int cbi = bt * 16 + i;
            t[i] = *(const unsigned int*)(lut8 +
                    ((size_t)((cbi << 4) + k) << 8) + (lane << 2));
        }
        #pragma unroll
        for (int i = 0; i < 16; ++i) {
            accLo += t[i] & 0x00FF00FFu;          // couts 4L, 4L+2
            accHi += (t[i] >> 8) & 0x00FF00FFu;   // couts 4L+1, 4L+3
        }
    }

    res[pos][lane * 2]     = accLo;
    res[pos][lane * 2 + 1] = accHi;
    __syncthreads();

    // ---- epilogue: thread t owns cout = t; int4 store of 4 consecutive r ----
    const float lsf = lut_s[0];
    const float osf = out_s[0];
    const float ozf = (float)out_z[0];

    const int co   = tid;
    const int c    = co & 3;
    const int u    = (co >> 2) * 2 + (c & 1);  // word index within row
    const int half = c >> 1;                   // u16 half within word
    const float bf = biasf2[co];

    int4 ov;
    int* ovp = (int*)&ov;
    #pragma unroll
    for (int p = 0; p < 4; ++p) {
        const unsigned int vv = res[p][u];
        const int sv = (int)((vv >> (16 * half)) & 0xffffu);
        float f = (float)sv * lsf + bf;        // = dequant sum + bias
        f = fmaxf(f, 0.0f) / osf + ozf;
        f = fminf(fmaxf(f, -128.0f), 127.0f);
        ovp[p] = (int)rintf(f);
    }
    *(int4*)(out + (size_t)(b * COUT_ + co) * L_ + r0) = ov;
}

extern "C" void kernel_launch(void* const* d_in, const int* in_sizes, int n_in,
                              void* d_out, int out_size, void* d_ws, size_t ws_size,
                              hipStream_t stream)
{
    const int*   x_q    = (const int*)  d_in[0];
    const float* x_s    = (const float*)d_in[1];
    const int*   x_z    = (const int*)  d_in[2];
    const int*   c_q    = (const int*)  d_in[3];
    const float* c_s    = (const float*)d_in[4];
    const int*   c_z    = (const int*)  d_in[5];
    const int*   lut_q  = (const int*)  d_in[6];
    const float* lut_s  = (const float*)d_in[7];
    const int*   lut_z  = (const int*)  d_in[8];
    const int*   bias_q = (const int*)  d_in[9];
    const float* bias_s = (const float*)d_in[10];
    const int*   bias_z = (const int*)  d_in[11];
    const float* out_s  = (const float*)d_in[12];
    const int*   out_z  = (const int*)  d_in[13];

    char* ws = (char*)d_ws;
    unsigned char* idx8 = (unsigned char*)(ws + WS_IDX);
    unsigned char* lut8 = (unsigned char*)(ws + WS_LUT8);
    float* cft    = (float*)(ws + WS_CFT);
    float* y2fp   = (float*)(ws + WS_Y2);
    float* biasf2 = (float*)(ws + WS_BF2);

    amm_pack<<<dim3(261), 256, 0, stream>>>(lut_q, lut_s, lut_z,
                                            c_q, c_s, c_z, x_s,
                                            bias_q, bias_s, bias_z,
                                            lut8, cft, y2fp, biasf2);

    amm_phase1<<<dim3(NCB_, B_), 256, 0, stream>>>(x_q, x_z, cft, y2fp, idx8);

    amm_phase2<<<dim3(N_ / 4), 256, 0, stream>>>(
        idx8, lut8, lut_s, biasf2, out_s, out_z, (int*)d_out);
}

// Round 9
// 26.706 us; speedup vs baseline: 32.1627x; 1.1686x over previous
//
#include <hip/hip_runtime.h>
#include <math.h>

// Problem constants (fixed by the reference)
constexpr int B_    = 8;
constexpr int CIN_  = 128;
constexpr int H_    = 28;
constexpr int W_    = 28;
constexpr int COUT_ = 256;
constexpr int OH_   = 28;
constexpr int OW_   = 28;
constexpr int L_    = OH_ * OW_;     // 784
constexpr int N_    = B_ * L_;       // 6272
constexpr int NCB_  = 64;
constexpr int K_    = 16;
constexpr int SUB_  = 18;            // 2 channels x 9 taps

// ws layout (byte offsets). idx layout [cb][n] (cb-major).
constexpr size_t WS_IDX  = 0;                  // 64*6272 uchar = 401408 B
constexpr size_t WS_LUT8 = 0x100000;           // 262144 uchar = 256 KB
constexpr size_t WS_BF2  = 0x180000;           // 256 f32 (bias + folded consts)

// ---------------------------------------------------------------------------
// K1: fused phase1 + pack. Blocks 0..511 = (cb = bx&63, b = bx>>6) argmin
// blocks, fully self-contained (centroid prep + y2 computed in-block from
// c_q — same double arithmetic & order as before, bit-identical results).
// Blocks 512..767 pack lut int32 -> biased uint8 (v+128); block 768 preps
// bias with the (8192 + 64*lut_z)*lut_s constant folded in.
// Pack blocks are independent of argmin blocks (no intra-kernel dependency).
// ---------------------------------------------------------------------------
__global__ __launch_bounds__(256, 2) void amm_k1(
    const int* __restrict__ x_q, const int* __restrict__ x_z,
    const int* __restrict__ c_q, const float* __restrict__ c_s,
    const int* __restrict__ c_z, const float* __restrict__ x_s,
    const int* __restrict__ lut_q, const float* __restrict__ lut_s,
    const int* __restrict__ lut_z,
    const int* __restrict__ bias_q, const float* __restrict__ bias_s,
    const int* __restrict__ bias_z,
    unsigned char* __restrict__ idx8, unsigned char* __restrict__ lut8,
    float* __restrict__ biasf2)
{
    const int bx  = blockIdx.x;
    const int tid = threadIdx.x;

    if (bx >= 512) {                       // ---- pack role ----
        const int pb = bx - 512;
        if (pb < 256) {
            const int i = pb * 1024 + tid * 4;       // covers 262144 exactly
            const int4 v = *(const int4*)(lut_q + i);
            uchar4 o;
            o.x = (unsigned char)(v.x + 128);
            o.y = (unsigned char)(v.y + 128);
            o.z = (unsigned char)(v.z + 128);
            o.w = (unsigned char)(v.w + 128);
            *(uchar4*)(lut8 + i) = o;
        } else {
            const double ls = (double)lut_s[0];
            const double c0 = (8192.0 + 64.0 * (double)lut_z[0]) * ls;
            biasf2[tid] = (float)((double)(bias_q[tid] - bias_z[0]) *
                                  (double)bias_s[0] - c0);
        }
        return;
    }

    // ---- argmin role ----
    const int cb = bx & 63;
    const int b  = bx >> 6;

    __shared__ float sx[2][900];     // 30x30 zero-padded, 7.2 KB
    __shared__ float c_lds[288];     // [s][k] k-major, float(c_q - zc)
    __shared__ float y2_lds[16];

    const int zc = c_z[cb];
    // zero padded tiles; stage centroids (transpose [k][s] -> [s][k])
    for (int i = tid; i < 1800; i += 256) ((float*)sx)[i] = 0.0f;
    for (int i = tid; i < 288; i += 256) {
        const int k = i / SUB_, s = i - k * SUB_;
        c_lds[s * 16 + k] = (float)(c_q[cb * 288 + i] - zc);   // exact int
    }
    __syncthreads();

    const int xz = x_z[0];
    // fill interior: i = c2*784 + r
    for (int i = tid; i < 2 * 784; i += 256) {
        const int c2 = i >= 784;
        const int r  = i - c2 * 784;
        const int h  = r / 28;
        const int w  = r - h * 28;
        sx[c2][(h + 1) * 30 + (w + 1)] =
            (float)(x_q[(size_t)(b * CIN_ + 2 * cb + c2) * L_ + r] - xz);
    }
    if (tid < 16) {                 // y2 in double, same order as before
        const double csf = (double)c_s[cb];
        const double den = (double)x_s[0] * csf;
        double s2 = 0.0;
        for (int s = 0; s < SUB_; ++s) {
            const double d = (double)c_lds[s * 16 + tid] * csf;
            s2 += d * d;
        }
        y2_lds[tid] = (float)(int)rint(s2 / den);   // < 2^24 -> exact in f32
    }
    __syncthreads();

    if (tid < 196) {
        // taps for 4 interleaved positions {t, t+196, t+392, t+588}
        float tap[4][SUB_];
        int   posr[4];
        #pragma unroll
        for (int ps = 0; ps < 4; ++ps) {
            const int p  = tid + 196 * ps;
            posr[ps] = p;
            const int oh = p / 28;
            const int ow = p - oh * 28;
            const int base = oh * 30 + ow;   // padded origin handles the -1
            #pragma unroll
            for (int c2 = 0; c2 < 2; ++c2)
                #pragma unroll
                for (int kh = 0; kh < 3; ++kh)
                    #pragma unroll
                    for (int kw = 0; kw < 3; ++kw)
                        tap[ps][c2 * 9 + kh * 3 + kw] =
                            sx[c2][base + kh * 30 + kw];
        }

        float bestd[4] = {3.0e38f, 3.0e38f, 3.0e38f, 3.0e38f};
        int   bestk[4] = {0, 0, 0, 0};

        #pragma unroll
        for (int kc = 0; kc < 4; ++kc) {
            float acc[4][4];
            #pragma unroll
            for (int ps = 0; ps < 4; ++ps)
                #pragma unroll
                for (int kk = 0; kk < 4; ++kk) acc[ps][kk] = 0.0f;

            #pragma unroll
            for (int s = 0; s < SUB_; ++s) {
                const float4 c4 = *(const float4*)&c_lds[s * 16 + kc * 4];
                #pragma unroll
                for (int ps = 0; ps < 4; ++ps) {
                    const float xs = tap[ps][s];
                    acc[ps][0] = fmaf(xs, c4.x, acc[ps][0]);
                    acc[ps][1] = fmaf(xs, c4.y, acc[ps][1]);
                    acc[ps][2] = fmaf(xs, c4.z, acc[ps][2]);
                    acc[ps][3] = fmaf(xs, c4.w, acc[ps][3]);
                }
            }
            // argmin update, k ascending (strict < => first-occurrence min)
            #pragma unroll
            for (int kk = 0; kk < 4; ++kk) {
                const float yk = y2_lds[kc * 4 + kk];
                #pragma unroll
                for (int ps = 0; ps < 4; ++ps) {
                    const float d = fmaf(-2.0f, acc[ps][kk], yk);
                    if (d < bestd[ps]) { bestd[ps] = d; bestk[ps] = kc * 4 + kk; }
                }
            }
        }

        unsigned char* op = idx8 + (size_t)cb * N_ + b * L_;
        #pragma unroll
        for (int ps = 0; ps < 4; ++ps)
            op[posr[ps]] = (unsigned char)bestk[ps];   // coalesced across lanes
    }
}

// ---------------------------------------------------------------------------
// K2 (= R8 phase2, unchanged): grid 1568 x 256; each WAVE owns one position.
// Biased-uint8 LUT rows; uniform idx dword loads; 16-deep load batches;
// packed-u16 carry-free accumulation; LDS transpose epilogue; int4 stores.
// ---------------------------------------------------------------------------
__global__ __launch_bounds__(256, 6) void amm_phase2(
    const unsigned char* __restrict__ idx8, const unsigned char* __restrict__ lut8,
    const float* __restrict__ lut_s, const float* __restrict__ biasf2,
    const float* __restrict__ out_s, const int* __restrict__ out_z,
    int* __restrict__ out)
{
    const int tid  = threadIdx.x;
    const int lane = tid & 63;
    const int w    = __builtin_amdgcn_readfirstlane(tid >> 6);
    const int nb   = blockIdx.x * 4;
    const int b    = nb / L_;          // uniform; 784%4==0 so no b crossing
    const int r0   = nb - b * L_;
    const int pos  = w;                // wave id = position within block
    const int sh   = 8 * pos;

    __shared__ unsigned int res[4][130];   // [pos][128 words = 256 couts] +pad

    unsigned int accLo = 0, accHi = 0;   // packed u16 pairs
    #pragma unroll
    for (int bt = 0; bt < 4; ++bt) {
        unsigned int kw[16];
        #pragma unroll
        for (int i = 0; i < 16; ++i) {
            const int cbi = bt * 16 + i;
            kw[i] = *(const unsigned int*)(idx8 + (size_t)cbi * N_ + nb);
        }
        unsigned int t[16];
        #pragma unroll
        for (int i = 0; i < 16; ++i) {
            const unsigned int k = (kw[i] >> sh) & 0xffu;
            const int cbi = bt * 16 + i;
            t[i] = *(const unsigned int*)(lut8 +
                    ((size_t)((cbi << 4) + k) << 8) + (lane << 2));
        }
        #pragma unroll
        for (int i = 0; i < 16; ++i) {
            accLo += t[i] & 0x00FF00FFu;          // couts 4L, 4L+2
            accHi += (t[i] >> 8) & 0x00FF00FFu;   // couts 4L+1, 4L+3
        }
    }

    res[pos][lane * 2]     = accLo;
    res[pos][lane * 2 + 1] = accHi;
    __syncthreads();

    const float lsf = lut_s[0];
    const float osf = out_s[0];
    const float ozf = (float)out_z[0];

    const int co   = tid;
    const int c    = co & 3;
    const int u    = (co >> 2) * 2 + (c & 1);  // word index within row
    const int half = c >> 1;                   // u16 half within word
    const float bf = biasf2[co];

    int4 ov;
    int* ovp = (int*)&ov;
    #pragma unroll
    for (int p = 0; p < 4; ++p) {
        const unsigned int vv = res[p][u];
        const int sv = (int)((vv >> (16 * half)) & 0xffffu);
        float f = (float)sv * lsf + bf;        // = dequant sum + bias
        f = fmaxf(f, 0.0f) / osf + ozf;
        f = fminf(fmaxf(f, -128.0f), 127.0f);
        ovp[p] = (int)rintf(f);
    }
    *(int4*)(out + (size_t)(b * COUT_ + co) * L_ + r0) = ov;
}

extern "C" void kernel_launch(void* const* d_in, const int* in_sizes, int n_in,
                              void* d_out, int out_size, void* d_ws, size_t ws_size,
                              hipStream_t stream)
{
    const int*   x_q    = (const int*)  d_in[0];
    const float* x_s    = (const float*)d_in[1];
    const int*   x_z    = (const int*)  d_in[2];
    const int*   c_q    = (const int*)  d_in[3];
    const float* c_s    = (const float*)d_in[4];
    const int*   c_z    = (const int*)  d_in[5];
    const int*   lut_q  = (const int*)  d_in[6];
    const float* lut_s  = (const float*)d_in[7];
    const int*   lut_z  = (const int*)  d_in[8];
    const int*   bias_q = (const int*)  d_in[9];
    const float* bias_s = (const float*)d_in[10];
    const int*   bias_z = (const int*)  d_in[11];
    const float* out_s  = (const float*)d_in[12];
    const int*   out_z  = (const int*)  d_in[13];

    char* ws = (char*)d_ws;
    unsigned char* idx8 = (unsigned char*)(ws + WS_IDX);
    unsigned char* lut8 = (unsigned char*)(ws + WS_LUT8);
    float* biasf2 = (float*)(ws + WS_BF2);

    amm_k1<<<dim3(769), 256, 0, stream>>>(x_q, x_z, c_q, c_s, c_z, x_s,
                                          lut_q, lut_s, lut_z,
                                          bias_q, bias_s, bias_z,
                                          idx8, lut8, biasf2);

    amm_phase2<<<dim3(N_ / 4), 256, 0, stream>>>(
        idx8, lut8, lut_s, biasf2, out_s, out_z, (int*)d_out);
}